// Round 4
// baseline (311.281 us; speedup 1.0000x reference)
//
#include <hip/hip_runtime.h>
#include <math.h>

#define EPSREG 1e-5f
#define NBLOCKS 512

typedef float vf4 __attribute__((ext_vector_type(4)));   // clang-native float4

// ---------------------------------------------------------------------------
// Fused persistent kernel: stats -> grid barrier -> per-thread solve -> apply.
//
// x viewed as vf4[npos*64]: element (pos, c) at index pos*64 + c.
// Thread owns channel c = tid&63 throughout.
// Phase 1: (block, lane=tid>>6) accumulates over a contiguous pos slice;
//          block-reduce in LDS; 14 device-scope atomicAdds per channel.
// Barrier: atomic counter, all 512 blocks co-resident (cap = 2048 blocks).
// Phase 2: every thread redoes the tiny 4x4 Cholesky+inverse+affine-fold
//          for its own channel, straight into registers (no params buffer).
// Phase 3: block applies to the SAME chunk it read in phase 1 (L2/L3 hot);
//          nontemporal stores for the output stream.
// ---------------------------------------------------------------------------
__global__ __launch_bounds__(256) void fused_kernel(const vf4* __restrict__ x,
                                                    const float* __restrict__ weight, // (4,4,64)
                                                    const float* __restrict__ bias,   // (4,64)
                                                    vf4* __restrict__ out,
                                                    float* __restrict__ stats,        // 14*64
                                                    unsigned int* __restrict__ counter,
                                                    int pps,                          // positions per slice
                                                    float inv_n) {
    int tid  = threadIdx.x;
    int c    = tid & 63;
    int lane = tid >> 6;                       // 0..3
    int s    = blockIdx.x * 4 + lane;          // slice id

    // ---------------- Phase 1: sufficient statistics ----------------
    const vf4* xp = x + (size_t)s * pps * 64 + c;

    float a0=0.f,a1=0.f,a2=0.f,a3=0.f;
    float p00=0.f,p01=0.f,p02=0.f,p03=0.f;
    float p11=0.f,p12=0.f,p13=0.f;
    float p22=0.f,p23=0.f,p33=0.f;

    for (int it = 0; it < pps; it += 8) {
        vf4 v[8];
        #pragma unroll
        for (int u = 0; u < 8; ++u) v[u] = xp[(it + u) * 64];   // 8 loads in flight
        #pragma unroll
        for (int u = 0; u < 8; ++u) {
            float x0 = v[u].x, x1 = v[u].y, x2 = v[u].z, x3 = v[u].w;
            a0 += x0; a1 += x1; a2 += x2; a3 += x3;
            p00 += x0*x0; p01 += x0*x1; p02 += x0*x2; p03 += x0*x3;
            p11 += x1*x1; p12 += x1*x2; p13 += x1*x3;
            p22 += x2*x2; p23 += x2*x3;
            p33 += x3*x3;
        }
    }

    __shared__ float sm[14 * 256];
    {
        float vals[14] = {a0,a1,a2,a3,p00,p01,p02,p03,p11,p12,p13,p22,p23,p33};
        #pragma unroll
        for (int k = 0; k < 14; ++k) sm[k * 256 + tid] = vals[k];
    }
    __syncthreads();

    if (tid < 64) {
        #pragma unroll
        for (int k = 0; k < 14; ++k) {
            float v = sm[k*256 + tid] + sm[k*256 + 64 + tid]
                    + sm[k*256 + 128 + tid] + sm[k*256 + 192 + tid];
            atomicAdd(&stats[k * 64 + tid], v);     // device-scope by default
        }
    }
    __syncthreads();                                // all block atomics issued & drained

    // ---------------- Grid barrier (all 512 blocks co-resident) ----------------
    if (tid == 0) {
        __threadfence();                            // agent-scope release of our adds
        __hip_atomic_fetch_add(counter, 1u, __ATOMIC_ACQ_REL, __HIP_MEMORY_SCOPE_AGENT);
        while (__hip_atomic_load(counter, __ATOMIC_ACQUIRE, __HIP_MEMORY_SCOPE_AGENT)
               < (unsigned int)NBLOCKS) {
            __builtin_amdgcn_s_sleep(8);
        }
    }
    __syncthreads();

    // ---------------- Phase 2: per-thread 4x4 solve for channel c ----------------
    float st[14];
    #pragma unroll
    for (int k = 0; k < 14; ++k)
        st[k] = __hip_atomic_load(&stats[k*64 + c], __ATOMIC_RELAXED, __HIP_MEMORY_SCOPE_AGENT);

    float m0 = st[0]*inv_n, m1 = st[1]*inv_n, m2 = st[2]*inv_n, m3 = st[3]*inv_n;
    float c00 = st[4]*inv_n  - m0*m0 + EPSREG;
    float c01 = st[5]*inv_n  - m0*m1;
    float c02 = st[6]*inv_n  - m0*m2;
    float c03 = st[7]*inv_n  - m0*m3;
    float c11 = st[8]*inv_n  - m1*m1 + EPSREG;
    float c12 = st[9]*inv_n  - m1*m2;
    float c13 = st[10]*inv_n - m1*m3;
    float c22 = st[11]*inv_n - m2*m2 + EPSREG;
    float c23 = st[12]*inv_n - m2*m3;
    float c33 = st[13]*inv_n - m3*m3 + EPSREG;

    // Cholesky (lower)
    float l00 = sqrtf(c00);
    float l10 = c01 / l00, l20 = c02 / l00, l30 = c03 / l00;
    float l11 = sqrtf(c11 - l10*l10);
    float l21 = (c12 - l20*l10) / l11;
    float l31 = (c13 - l30*l10) / l11;
    float l22 = sqrtf(c22 - l20*l20 - l21*l21);
    float l32 = (c23 - l30*l20 - l31*l21) / l22;
    float l33 = sqrtf(c33 - l30*l30 - l31*l31 - l32*l32);

    // Inverse of lower triangular
    float i00 = 1.f / l00, i11 = 1.f / l11, i22 = 1.f / l22, i33 = 1.f / l33;
    float i10 = -i11 * (l10 * i00);
    float i20 = -i22 * (l20 * i00 + l21 * i10);
    float i21 = -i22 * (l21 * i11);
    float i30 = -i33 * (l30 * i00 + l31 * i10 + l32 * i20);
    float i31 = -i33 * (l31 * i11 + l32 * i21);
    float i32 = -i33 * (l32 * i22);

    float Li[4][4] = {{i00, 0.f, 0.f, 0.f},
                      {i10, i11, 0.f, 0.f},
                      {i20, i21, i22, 0.f},
                      {i30, i31, i32, i33}};

    // M = W_c @ Linv_c folded with bias; all in registers.
    float M[16], b[4];
    #pragma unroll
    for (int i = 0; i < 4; ++i) {
        float w0 = weight[(i*4 + 0)*64 + c];
        float w1 = weight[(i*4 + 1)*64 + c];
        float w2 = weight[(i*4 + 2)*64 + c];
        float w3 = weight[(i*4 + 3)*64 + c];
        #pragma unroll
        for (int j = 0; j < 4; ++j)
            M[i*4 + j] = w0*Li[0][j] + w1*Li[1][j] + w2*Li[2][j] + w3*Li[3][j];
        b[i] = bias[i*64 + c];
    }

    // ---------------- Phase 3: apply to this block's own chunk ----------------
    // Chunk = the 4 slices this block already read -> L2/L3 hot.
    const vf4* xc = x   + (size_t)blockIdx.x * 4 * pps * 64;
    vf4*       oc = out + (size_t)blockIdx.x * 4 * pps * 64;

    for (int it = 0; it < pps; it += 4) {
        vf4 v[4];
        #pragma unroll
        for (int u = 0; u < 4; ++u) v[u] = xc[(it + u) * 256 + tid];
        #pragma unroll
        for (int u = 0; u < 4; ++u) {
            float x0 = v[u].x - m0, x1 = v[u].y - m1, x2 = v[u].z - m2, x3 = v[u].w - m3;
            vf4 o;
            o.x = M[0]*x0  + M[1]*x1  + M[2]*x2  + M[3]*x3  + b[0];
            o.y = M[4]*x0  + M[5]*x1  + M[6]*x2  + M[7]*x3  + b[1];
            o.z = M[8]*x0  + M[9]*x1  + M[10]*x2 + M[11]*x3 + b[2];
            o.w = M[12]*x0 + M[13]*x1 + M[14]*x2 + M[15]*x3 + b[3];
            __builtin_nontemporal_store(o, &oc[(it + u) * 256 + tid]);
        }
    }
}

extern "C" void kernel_launch(void* const* d_in, const int* in_sizes, int n_in,
                              void* d_out, int out_size, void* d_ws, size_t ws_size,
                              hipStream_t stream) {
    const float* x      = (const float*)d_in[0];   // (32,64,64,64,4) fp32
    const float* weight = (const float*)d_in[1];   // (4,4,64)
    const float* bias   = (const float*)d_in[2];   // (4,64)
    vf4* out = (vf4*)d_out;

    float*        stats   = (float*)d_ws;                       // 14*64 floats
    unsigned int* counter = (unsigned int*)((char*)d_ws + 4096);

    int n_elem = in_sizes[0];        // 33554432
    int npos   = n_elem / 256;       // 131072 spatial positions
    int pps    = npos / (NBLOCKS * 4); // 64 positions per slice

    // zero stats + barrier counter (poisoned to 0xAA before every call)
    (void)hipMemsetAsync(d_ws, 0, 8192, stream);

    fused_kernel<<<NBLOCKS, 256, 0, stream>>>((const vf4*)x, weight, bias, out,
                                              stats, counter, pps,
                                              1.0f / (float)npos);
}